// Round 4
// baseline (281.070 us; speedup 1.0000x reference)
//
#include <hip/hip_runtime.h>
#include <hip/hip_fp16.h>
#include <stdint.h>

// Problem: B=4,Q=75,C=5 -> 1500 groups; D=512; P=H*W=36.
// Inputs fp32, outputs fp32 (per reference dtypes; round-3 post-mortem: the
// identical 2.3516 error across structurally different kernels == bf16 pairs
// packed into an fp32 output buffer -> adjacent-score mispairing).
#define NGRP 1500
#define DD 512
#define PP 36
#define DP (DD*PP)        // 18432 fp32 per group per tensor
#define SWEEPS 19         // 18 sweeps x 28 rows + 1 sweep x 8 rows = 512 rows
#define SCALE_CLS 7.0f
#define EPS 1e-12f

__device__ __forceinline__ uint32_t packh2(float a, float b){
  __half2 h = __floats2half2_rn(a, b);
  union{__half2 h; uint32_t u;} z; z.h = h; return z.u;
}
__device__ __forceinline__ float2 unpackh2(uint32_t v){
  union{uint32_t u; __half2 h;} z; z.u = v;
  return __half22float2(z.h);
}
__device__ __forceinline__ float waveRed(float x){
  #pragma unroll
  for (int off = 32; off; off >>= 1) x += __shfl_xor(x, off, 64);
  return x;
}

// One block per (b,q,c) group, 256 threads.
// Sweep = 28 rows x 9 float4 column-chunks = 252 active threads, coalesced.
// Thread (r,c) owns positions 4c..4c+3 of rows r+28k; fp16 copy of its stream
// stays in registers (keepT/keepR) for the fuse phase. Ranking stats fp32-exact.
__global__ __launch_bounds__(256, 2)
void topk_fuse(const float* __restrict__ gtrain,
               const float* __restrict__ gtest,
               const int* __restrict__ Kp,
               float* __restrict__ out)
{
  __shared__ float s_pt[252], s_pr[252];   // per-sweep row partials
  __shared__ float s_tm[28],  s_rm[28];    // per-sweep row means
  __shared__ float s_q[PP], s_e[PP];       // per-pos sumsq (test/train)
  __shared__ float s_a[PP], s_b[PP];       // per-pos dot with other mean
  __shared__ float s_st[PP], s_sr[PP];     // ranking scores
  __shared__ float s_nt[PP], s_nr[PP];     // per-pos norms
  __shared__ float s_wt[PP], s_wr[PP];     // fuse weights

  const int t    = threadIdx.x;
  const int lane = t & 63;
  const int wave = t >> 6;
  const int g    = blockIdx.x;
  const int K    = Kp[0];
  const int c    = t % 9;                  // float4 chunk -> positions 4c..4c+3
  const int r    = t / 9;                  // row slot in sweep (0..27 for t<252)

  const float4* gt4 = (const float4*)(gtest  + (size_t)g * DP);
  const float4* gr4 = (const float4*)(gtrain + (size_t)g * DP);

  if (t < PP) { s_q[t] = 0.f; s_e[t] = 0.f; s_a[t] = 0.f; s_b[t] = 0.f; }

  uint32_t keepT[2*SWEEPS], keepR[2*SWEEPS];   // fp16x2-packed stream copy
  float4 q4 = {0,0,0,0}, e4 = {0,0,0,0}, a4 = {0,0,0,0}, b4 = {0,0,0,0};
  float pm2 = 0.f, pr2 = 0.f, pmr = 0.f;

  float4 T = {0,0,0,0}, R = {0,0,0,0};
  if (t < 252) { int i0 = r*9 + c; T = gt4[i0]; R = gr4[i0]; }

  #pragma unroll
  for (int k = 0; k < SWEEPS; ++k) {
    // prefetch next sweep
    float4 Tn = {0,0,0,0}, Rn = {0,0,0,0};
    if (k < SWEEPS-1) {
      bool nact = (k+1 < SWEEPS-1) ? (t < 252) : (t < 72);
      if (nact) { int ni = (r + 28*(k+1))*9 + c; Tn = gt4[ni]; Rn = gr4[ni]; }
    }
    const bool cact = (k < SWEEPS-1) ? (t < 252) : (t < 72);

    if (cact) {
      s_pt[r*9 + c] = T.x + T.y + T.z + T.w;
      s_pr[r*9 + c] = R.x + R.y + R.z + R.w;
    }
    __syncthreads();

    const int rows = (k < SWEEPS-1) ? 28 : 8;
    if (t < rows) {
      float st = 0.f, sr = 0.f;
      #pragma unroll
      for (int j = 0; j < 9; ++j) { st += s_pt[t*9 + j]; sr += s_pr[t*9 + j]; }
      float tm = st * (1.0f/36.0f), rm = sr * (1.0f/36.0f);
      s_tm[t] = tm; s_rm[t] = rm;
      pm2 += tm*tm; pr2 += rm*rm; pmr += tm*rm;  // mean-cosine partials
    }
    __syncthreads();

    if (cact) {
      float tm = s_tm[r], rm = s_rm[r];
      q4.x += T.x*T.x; q4.y += T.y*T.y; q4.z += T.z*T.z; q4.w += T.w*T.w;
      e4.x += R.x*R.x; e4.y += R.y*R.y; e4.z += R.z*R.z; e4.w += R.w*R.w;
      a4.x += T.x*rm;  a4.y += T.y*rm;  a4.z += T.z*rm;  a4.w += T.w*rm;
      b4.x += R.x*tm;  b4.y += R.y*tm;  b4.z += R.z*tm;  b4.w += R.w*tm;
      keepT[2*k] = packh2(T.x, T.y); keepT[2*k+1] = packh2(T.z, T.w);
      keepR[2*k] = packh2(R.x, R.y); keepR[2*k+1] = packh2(R.z, R.w);
    } else {
      keepT[2*k] = 0u; keepT[2*k+1] = 0u; keepR[2*k] = 0u; keepR[2*k+1] = 0u;
    }
    T = Tn; R = Rn;
  }

  // merge per-thread position stats (positions 4c..4c+3)
  if (t < 252) {
    int p0 = c*4;
    atomicAdd(&s_q[p0+0], q4.x); atomicAdd(&s_q[p0+1], q4.y);
    atomicAdd(&s_q[p0+2], q4.z); atomicAdd(&s_q[p0+3], q4.w);
    atomicAdd(&s_e[p0+0], e4.x); atomicAdd(&s_e[p0+1], e4.y);
    atomicAdd(&s_e[p0+2], e4.z); atomicAdd(&s_e[p0+3], e4.w);
    atomicAdd(&s_a[p0+0], a4.x); atomicAdd(&s_a[p0+1], a4.y);
    atomicAdd(&s_a[p0+2], a4.z); atomicAdd(&s_a[p0+3], a4.w);
    atomicAdd(&s_b[p0+0], b4.x); atomicAdd(&s_b[p0+1], b4.y);
    atomicAdd(&s_b[p0+2], b4.z); atomicAdd(&s_b[p0+3], b4.w);
  }
  // global (mean-cosine) score: row partials live in threads 0..27 (wave 0)
  if (wave == 0) {
    float m2 = waveRed(pm2), r2 = waveRed(pr2), mr = waveRed(pmr);
    if (lane == 0) {
      float n1 = fmaxf(sqrtf(m2), EPS), n2 = fmaxf(sqrtf(r2), EPS);
      out[g] = SCALE_CLS * mr / (n1 * n2);
    }
  }
  __syncthreads();

  // per-position norms + ranking scores (positive per-group factors dropped)
  if (wave < 2 && lane < PP) {
    float q  = wave ? s_e[lane] : s_q[lane];
    float dm = wave ? s_b[lane] : s_a[lane];
    float n  = fmaxf(sqrtf(q), EPS);
    if (wave) { s_nr[lane] = n; s_sr[lane] = dm / n; }
    else      { s_nt[lane] = n; s_st[lane] = dm / n; }
  }
  __syncthreads();

  // top-K via ranks (jnp.top_k ties: lower index wins)
  if (wave < 2 && lane < PP) {
    const float* sc = wave ? s_sr : s_st;
    const float* nn = wave ? s_nr : s_nt;
    float*       w  = wave ? s_wr : s_wt;
    float mine = sc[lane];
    int rank = 0;
    #pragma unroll
    for (int p = 0; p < PP; ++p) {
      float o = sc[p];
      rank += ((o > mine) || (o == mine && p < lane)) ? 1 : 0;
    }
    w[lane] = (rank < K) ? (1.0f / nn[lane]) : 0.f;
  }
  __syncthreads();

  // fuse phase: weighted column sums from register-held fp16 copy,
  // reduced with the same 2-barrier per-sweep skeleton. 1/K cancels in l2norm.
  float wt0=0,wt1=0,wt2=0,wt3=0, wr0=0,wr1=0,wr2=0,wr3=0;
  if (t < 252) {
    wt0 = s_wt[4*c+0]; wt1 = s_wt[4*c+1]; wt2 = s_wt[4*c+2]; wt3 = s_wt[4*c+3];
    wr0 = s_wr[4*c+0]; wr1 = s_wr[4*c+1]; wr2 = s_wr[4*c+2]; wr3 = s_wr[4*c+3];
  }
  float U2 = 0.f, V2 = 0.f, UV = 0.f;
  #pragma unroll
  for (int k = 0; k < SWEEPS; ++k) {
    const bool cact = (k < SWEEPS-1) ? (t < 252) : (t < 72);
    if (cact) {
      float2 t0 = unpackh2(keepT[2*k]), t1 = unpackh2(keepT[2*k+1]);
      float2 r0 = unpackh2(keepR[2*k]), r1 = unpackh2(keepR[2*k+1]);
      s_pt[r*9 + c] = t0.x*wt0 + t0.y*wt1 + t1.x*wt2 + t1.y*wt3;
      s_pr[r*9 + c] = r0.x*wr0 + r0.y*wr1 + r1.x*wr2 + r1.y*wr3;
    }
    __syncthreads();
    const int rows = (k < SWEEPS-1) ? 28 : 8;
    if (t < rows) {
      float u = 0.f, v = 0.f;
      #pragma unroll
      for (int j = 0; j < 9; ++j) { u += s_pt[t*9 + j]; v += s_pr[t*9 + j]; }
      U2 += u*u; V2 += v*v; UV += u*v;
    }
    __syncthreads();
  }
  if (wave == 0) {
    float u2 = waveRed(U2), v2 = waveRed(V2), uv = waveRed(UV);
    if (lane == 0) {
      float nu = fmaxf(sqrtf(u2), EPS), nv = fmaxf(sqrtf(v2), EPS);
      out[NGRP + g] = SCALE_CLS * uv / (nu * nv);
    }
  }
}

extern "C" void kernel_launch(void* const* d_in, const int* in_sizes, int n_in,
                              void* d_out, int out_size, void* d_ws, size_t ws_size,
                              hipStream_t stream)
{
  const float* ftrain = (const float*)d_in[0];
  const float* ftest  = (const float*)d_in[1];
  const int*   Kp     = (const int*)d_in[2];
  float*       out    = (float*)d_out;
  topk_fuse<<<NGRP, 256, 0, stream>>>(ftrain, ftest, Kp, out);
}

// Round 5
// 269.571 us; speedup vs baseline: 1.0427x; 1.0427x over previous
//
#include <hip/hip_runtime.h>
#include <stdint.h>

// Problem: B=4,Q=75,C=5 -> 1500 groups; D=512; P=H*W=36. fp32 in, fp32 out.
// Round-4 post-mortem: 134us with VALUBusy 9.9%, HBM 10% => barrier-latency
// bound (76 __syncthreads/block). This version: one unbarriered coalesced
// streaming pass, full fp32 stream kept in registers (152 VGPRs), ~7 barriers.
#define NGRP 1500
#define DD 512
#define PP 36
#define DP (DD*PP)        // 18432 fp32 per group per tensor
#define SWEEPS 19         // 18 sweeps x 252 + 1 sweep x 72 float4s = 4608
#define SCALE_CLS 7.0f
#define EPS 1e-12f

__device__ __forceinline__ float waveRed(float x){
  #pragma unroll
  for (int off = 32; off; off >>= 1) x += __shfl_xor(x, off, 64);
  return x;
}

// One block per (b,q,c) group, 256 threads.
// Thread t=(r,c): float4 column-chunk c (positions 4c..4c+3) of rows r+28k.
// Global float4 index (r+28k)*9+c == t + 252k  -> perfectly coalesced.
__global__ __launch_bounds__(256, 2)
void topk_fuse(const float* __restrict__ gtrain,
               const float* __restrict__ gtest,
               const int* __restrict__ Kp,
               float* __restrict__ out)
{
  __shared__ float s_rt[DD*9];             // per-row partials, test  (18.4 KB)
  __shared__ float s_rr[DD*9];             // per-row partials, train
  __shared__ float s_tm[DD], s_rm[DD];     // row means (4 KB)
  __shared__ float s_q[PP], s_e[PP];       // per-pos sumsq
  __shared__ float s_a[PP], s_b[PP];       // per-pos dot with other mean
  __shared__ float s_st[PP], s_sr[PP];     // ranking scores
  __shared__ float s_nt[PP], s_nr[PP];     // per-pos norms
  __shared__ float s_wt[PP], s_wr[PP];     // fuse weights
  __shared__ float s_red[12];

  const int t    = threadIdx.x;
  const int lane = t & 63;
  const int wave = t >> 6;
  const int g    = blockIdx.x;
  const int K    = Kp[0];
  const int c    = t % 9;
  const int r    = t / 9;
  const bool act = t < 252;

  const float4* gt4 = (const float4*)(gtest  + (size_t)g * DP);
  const float4* gr4 = (const float4*)(gtrain + (size_t)g * DP);

  if (t < PP) { s_q[t] = 0.f; s_e[t] = 0.f; s_a[t] = 0.f; s_b[t] = 0.f; }

  // ---- Phase 1: stream everything, no barriers. Keep fp32 copy in regs. ----
  float4 keepT[SWEEPS], keepR[SWEEPS];
  float4 q4 = {0,0,0,0}, e4 = {0,0,0,0};
  #pragma unroll
  for (int k = 0; k < SWEEPS; ++k) {
    const bool cact = (k < SWEEPS-1) ? act : (t < 72);
    float4 T = {0,0,0,0}, R = {0,0,0,0};
    if (cact) { int i = t + 252*k; T = gt4[i]; R = gr4[i]; }
    keepT[k] = T; keepR[k] = R;
    q4.x += T.x*T.x; q4.y += T.y*T.y; q4.z += T.z*T.z; q4.w += T.w*T.w;
    e4.x += R.x*R.x; e4.y += R.y*R.y; e4.z += R.z*R.z; e4.w += R.w*R.w;
    if (cact) {
      s_rt[t + 252*k] = T.x + T.y + T.z + T.w;   // linear -> conflict-free
      s_rr[t + 252*k] = R.x + R.y + R.z + R.w;
    }
  }
  __syncthreads();                                              // A

  // ---- Phase 2: all 512 row means at once (2 rows/thread) + mean-cosine ----
  float pm2 = 0.f, pr2 = 0.f, pmr = 0.f;
  #pragma unroll
  for (int h = 0; h < 2; ++h) {
    int d = t + 256*h;                     // stride-9 reads: 2-way max (free)
    float st = 0.f, sr = 0.f;
    #pragma unroll
    for (int j = 0; j < 9; ++j) { st += s_rt[d*9 + j]; sr += s_rr[d*9 + j]; }
    float tm = st * (1.0f/36.0f), rm = sr * (1.0f/36.0f);
    s_tm[d] = tm; s_rm[d] = rm;
    pm2 += tm*tm; pr2 += rm*rm; pmr += tm*rm;
  }
  pm2 = waveRed(pm2); pr2 = waveRed(pr2); pmr = waveRed(pmr);
  if (lane == 0) { s_red[wave] = pm2; s_red[4+wave] = pr2; s_red[8+wave] = pmr; }
  __syncthreads();                                              // B
  if (t == 0) {
    float m2 = s_red[0]+s_red[1]+s_red[2]+s_red[3];
    float r2 = s_red[4]+s_red[5]+s_red[6]+s_red[7];
    float mr = s_red[8]+s_red[9]+s_red[10]+s_red[11];
    float n1 = fmaxf(sqrtf(m2), EPS), n2 = fmaxf(sqrtf(r2), EPS);
    out[g] = SCALE_CLS * mr / (n1 * n2);
  }

  // ---- Phase 3: a/b dots from register stream vs LDS means ----
  float4 a4 = {0,0,0,0}, b4 = {0,0,0,0};
  #pragma unroll
  for (int k = 0; k < SWEEPS; ++k) {
    int d = r + 28*k; if (d > 511) d = 511;       // clamp (inactive lanes hold zeros)
    float tm = s_tm[d], rm = s_rm[d];             // 9-lane broadcast reads
    float4 T = keepT[k], R = keepR[k];
    a4.x += T.x*rm; a4.y += T.y*rm; a4.z += T.z*rm; a4.w += T.w*rm;
    b4.x += R.x*tm; b4.y += R.y*tm; b4.z += R.z*tm; b4.w += R.w*tm;
  }
  if (act) {
    int p0 = c*4;
    atomicAdd(&s_q[p0+0], q4.x); atomicAdd(&s_q[p0+1], q4.y);
    atomicAdd(&s_q[p0+2], q4.z); atomicAdd(&s_q[p0+3], q4.w);
    atomicAdd(&s_e[p0+0], e4.x); atomicAdd(&s_e[p0+1], e4.y);
    atomicAdd(&s_e[p0+2], e4.z); atomicAdd(&s_e[p0+3], e4.w);
    atomicAdd(&s_a[p0+0], a4.x); atomicAdd(&s_a[p0+1], a4.y);
    atomicAdd(&s_a[p0+2], a4.z); atomicAdd(&s_a[p0+3], a4.w);
    atomicAdd(&s_b[p0+0], b4.x); atomicAdd(&s_b[p0+1], b4.y);
    atomicAdd(&s_b[p0+2], b4.z); atomicAdd(&s_b[p0+3], b4.w);
  }
  __syncthreads();                                              // C

  // ---- Phase 4: norms + ranking scores (positive group factors dropped) ----
  if (wave < 2 && lane < PP) {
    float q  = wave ? s_e[lane] : s_q[lane];
    float dm = wave ? s_b[lane] : s_a[lane];
    float n  = fmaxf(sqrtf(q), EPS);
    if (wave) { s_nr[lane] = n; s_sr[lane] = dm / n; }
    else      { s_nt[lane] = n; s_st[lane] = dm / n; }
  }
  __syncthreads();                                              // D

  // ---- Phase 5: top-K via ranks (jnp ties: lower index wins) ----
  if (wave < 2 && lane < PP) {
    const float* sc = wave ? s_sr : s_st;
    const float* nn = wave ? s_nr : s_nt;
    float*       w  = wave ? s_wr : s_wt;
    float mine = sc[lane];
    int rank = 0;
    #pragma unroll
    for (int p = 0; p < PP; ++p) {
      float o = sc[p];
      rank += ((o > mine) || (o == mine && p < lane)) ? 1 : 0;
    }
    w[lane] = (rank < K) ? (1.0f / nn[lane]) : 0.f;
  }
  __syncthreads();                                              // E

  // ---- Phase 6: fuse from fp32 register stream (1/K cancels in l2norm) ----
  float wt0=0,wt1=0,wt2=0,wt3=0, wr0=0,wr1=0,wr2=0,wr3=0;
  if (act) {
    wt0 = s_wt[4*c+0]; wt1 = s_wt[4*c+1]; wt2 = s_wt[4*c+2]; wt3 = s_wt[4*c+3];
    wr0 = s_wr[4*c+0]; wr1 = s_wr[4*c+1]; wr2 = s_wr[4*c+2]; wr3 = s_wr[4*c+3];
  }
  #pragma unroll
  for (int k = 0; k < SWEEPS; ++k) {
    const bool cact = (k < SWEEPS-1) ? act : (t < 72);
    if (cact) {
      float4 T = keepT[k], R = keepR[k];
      s_rt[t + 252*k] = T.x*wt0 + T.y*wt1 + T.z*wt2 + T.w*wt3;
      s_rr[t + 252*k] = R.x*wr0 + R.y*wr1 + R.z*wr2 + R.w*wr3;
    }
  }
  __syncthreads();                                              // F
  float U2 = 0.f, V2 = 0.f, UV = 0.f;
  #pragma unroll
  for (int h = 0; h < 2; ++h) {
    int d = t + 256*h;
    float u = 0.f, v = 0.f;
    #pragma unroll
    for (int j = 0; j < 9; ++j) { u += s_rt[d*9 + j]; v += s_rr[d*9 + j]; }
    U2 += u*u; V2 += v*v; UV += u*v;
  }
  U2 = waveRed(U2); V2 = waveRed(V2); UV = waveRed(UV);
  if (lane == 0) { s_red[wave] = U2; s_red[4+wave] = V2; s_red[8+wave] = UV; }
  __syncthreads();                                              // G
  if (t == 0) {
    float u2 = s_red[0]+s_red[1]+s_red[2]+s_red[3];
    float v2 = s_red[4]+s_red[5]+s_red[6]+s_red[7];
    float uv = s_red[8]+s_red[9]+s_red[10]+s_red[11];
    float nu = fmaxf(sqrtf(u2), EPS), nv = fmaxf(sqrtf(v2), EPS);
    out[NGRP + g] = SCALE_CLS * uv / (nu * nv);
  }
}

extern "C" void kernel_launch(void* const* d_in, const int* in_sizes, int n_in,
                              void* d_out, int out_size, void* d_ws, size_t ws_size,
                              hipStream_t stream)
{
  const float* ftrain = (const float*)d_in[0];
  const float* ftest  = (const float*)d_in[1];
  const int*   Kp     = (const int*)d_in[2];
  float*       out    = (float*)d_out;
  topk_fuse<<<NGRP, 256, 0, stream>>>(ftrain, ftest, Kp, out);
}